// Round 15
// baseline (2652.338 us; speedup 1.0000x reference)
//
#include <hip/hip_runtime.h>

#define S_LEN 128
#define T_LEN 64
#define BSZ   64
#define EMBD  256
#define HID_  512
#define DHID_ 1024
#define VOC_  32000
#define HSTR  1024

typedef float  f4_t  __attribute__((ext_vector_type(4)));
typedef float  f32x4 __attribute__((ext_vector_type(4)));
typedef short  s16x8 __attribute__((ext_vector_type(8)));
typedef __bf16 bf16x8 __attribute__((ext_vector_type(8)));
typedef unsigned short u16x4 __attribute__((ext_vector_type(4)));
typedef int    i32x2 __attribute__((ext_vector_type(2)));

// ---------------- workspace layout ----------------
// float offsets:
#define WS_XWA  0ull
#define WS_XWB  (WS_XWA + 16777216ull)
#define WS_CS   (WS_XWB + 16777216ull)
#define WS_BAR  (WS_CS  + 131072ull)
#define WS_BF   (WS_BAR + 32768ull)
// ushort offsets within bf16 region:
#define U_X0B   0ull
#define U_HE0   (U_X0B + 2097152ull)
#define U_HE1   (U_HE0 + 8388608ull)
#define U_HD0   (U_HE1 + 8388608ull)
#define U_HD1   (U_HD0 + 4194304ull)
#define U_HSB   (U_HD1 + 4194304ull)
#define U_E0W   (U_HSB + 131072ull)
#define U_E1W   (U_E0W + 1048576ull)
#define U_D0W   (U_E1W + 4194304ull)
#define U_D1W   (U_D0W + 1048576ull)

__device__ __forceinline__ unsigned short f2bf(float x) {
    unsigned u = __builtin_bit_cast(unsigned, x);
    return (unsigned short)((u + 0x7fffu + ((u >> 16) & 1u)) >> 16);
}

// ---------------- coherent (LLC-scope) memory helpers ----------------
__device__ __forceinline__ f4_t sc_load4(const void* p) {
    f4_t v;
    asm volatile("global_load_dwordx4 %0, %1, off sc0 sc1" : "=v"(v) : "v"(p));
    return v;                               // NOT ready until a vmcnt wait
}
__device__ __forceinline__ int sc_load1(const int* p) {
    int v;
    asm volatile("global_load_dword %0, %1, off sc0 sc1\n\ts_waitcnt vmcnt(0)"
                 : "=v"(v) : "v"(p) : "memory");
    return v;
}
__device__ __forceinline__ void sc_store_int(int* p, int v) {
    asm volatile("global_store_dword %0, %1, off sc0 sc1" :: "v"(p), "v"(v) : "memory");
}
__device__ __forceinline__ void sc_store8(void* p, i32x2 v) {
    asm volatile("global_store_dwordx2 %0, %1, off sc0 sc1" :: "v"(p), "v"(v) : "memory");
}
__device__ __forceinline__ float g_load1(const float* p) {   // plain cached load, no wait
    float v;
    asm volatile("global_load_dword %0, %1, off" : "=v"(v) : "v"(p));
    return v;
}
__device__ __forceinline__ void wait_vm0() {
    asm volatile("s_waitcnt vmcnt(0)" ::: "memory");
}
__device__ __forceinline__ void wait_vm8() {
    asm volatile("s_waitcnt vmcnt(8)" ::: "memory");
}

__device__ __forceinline__ void gload_lds16(const void* g, void* l) {
    __builtin_amdgcn_global_load_lds(
        (const __attribute__((address_space(1))) void*)g,
        (__attribute__((address_space(3))) void*)l, 16, 0, 0);
}

__device__ __forceinline__ float sigmoidf_(float x) { return 1.f / (1.f + expf(-x)); }

// ---------------- fp32 -> bf16 conversion (single kernel, 4 weight segments) ----------------
__global__ __launch_bounds__(256) void f2b_multi_kernel(
    const float* __restrict__ p0, unsigned short* __restrict__ q0,
    const float* __restrict__ p1, unsigned short* __restrict__ q1,
    const float* __restrict__ p2, unsigned short* __restrict__ q2,
    const float* __restrict__ p3, unsigned short* __restrict__ q3)
{
    const int stride = gridDim.x * 256;
    for (int i = blockIdx.x * 256 + threadIdx.x; i < 2621440; i += stride) {
        const float* in; unsigned short* out; int o;
        if (i < 262144)       { in = p0; out = q0; o = i; }
        else if (i < 1310720) { in = p1; out = q1; o = i - 262144; }
        else if (i < 1572864) { in = p2; out = q2; o = i - 1310720; }
        else                  { in = p3; out = q3; o = i - 1572864; }
        const float4 v = reinterpret_cast<const float4*>(in)[o];
        u16x4 w = { f2bf(v.x), f2bf(v.y), f2bf(v.z), f2bf(v.w) };
        reinterpret_cast<u16x4*>(out)[o] = w;
    }
}

__global__ __launch_bounds__(256) void f2b_kernel(
    const float* __restrict__ in, unsigned short* __restrict__ out, int n4)
{
    const int stride = gridDim.x * 256;
    for (int i = blockIdx.x * 256 + threadIdx.x; i < n4; i += stride) {
        const float4 v = reinterpret_cast<const float4*>(in)[i];
        u16x4 o = { f2bf(v.x), f2bf(v.y), f2bf(v.z), f2bf(v.w) };
        reinterpret_cast<u16x4*>(out)[i] = o;
    }
}

// ---------------- embedding gathers (emit bf16), 4 tokens per 256-thr block ----------------
__global__ __launch_bounds__(256) void embed_src_kernel(
    const int* __restrict__ toks, const float* __restrict__ emb,
    unsigned short* __restrict__ out)
{
    const int i = blockIdx.x * 4 + (threadIdx.x >> 6);
    const int lane = threadIdx.x & 63;
    const int tok = toks[i];
    const float4 v = reinterpret_cast<const float4*>(emb + (size_t)tok * EMBD)[lane];
    u16x4 o = { f2bf(v.x), f2bf(v.y), f2bf(v.z), f2bf(v.w) };
    reinterpret_cast<u16x4*>(out + (size_t)i * EMBD)[lane] = o;
}

__global__ __launch_bounds__(256) void embed_dec_kernel(
    const int* __restrict__ sent, const int* __restrict__ targ,
    const float* __restrict__ emb, unsigned short* __restrict__ out)
{
    const int i = blockIdx.x * 4 + (threadIdx.x >> 6);
    const int lane = threadIdx.x & 63;
    const int t = i >> 6, b = i & 63;
    const int tok = (t == 0) ? sent[(S_LEN - 1) * BSZ + b] : targ[(t - 1) * BSZ + b];
    const float4 v = reinterpret_cast<const float4*>(emb + (size_t)tok * EMBD)[lane];
    u16x4 o = { f2bf(v.x), f2bf(v.y), f2bf(v.z), f2bf(v.w) };
    reinterpret_cast<u16x4*>(out + (size_t)i * EMBD)[lane] = o;
}

// ---------------- bf16 MFMA GEMM:  C = A[M,K] * B[N,K]^T + b1 (+ b2) ----------------
// tmode 0 (logits): n-major block order (B-tile L2 reuse), LDS-staged coalesced fp32
//   C-write (full-line stores, no write-allocate), optional softmax partials.
// tmode 1: C fp32 as (M/64, N, 64) = (T,N,B) for the scans.
__global__ __launch_bounds__(256) void gemm_bf16_kernel(
    const unsigned short* __restrict__ A, const unsigned short* __restrict__ B,
    const float* __restrict__ b1, const float* __restrict__ b2,
    float* __restrict__ C, int M, int N, int K, int nTN, int tmode,
    float* __restrict__ part)
{
    __shared__ __align__(16) char smem[34816];           // As(16K) + Bs(16K); epilogue: cst 64x132 f32
    unsigned short* As = (unsigned short*)smem;
    unsigned short* Bs = As + 128 * 64;
    __shared__ float prt[2][128][2];

    const int tid  = threadIdx.x;
    const int lane = tid & 63;
    const int wv   = tid >> 6;
    const int wm   = wv >> 1, wn = wv & 1;

    const int nwg = gridDim.x;
    const int q = nwg >> 3, r = nwg & 7;
    const int xcd = blockIdx.x & 7, io = blockIdx.x >> 3;
    const int wg = (xcd < r ? xcd * (q + 1) : r * (q + 1) + (xcd - r) * q) + io;
    int bm, bn;
    if (tmode == 0) { bm = (wg & 31) << 7; bn = (wg >> 5) << 7; }   // n-major (M=4096)
    else            { bm = (wg / nTN) * 128; bn = (wg % nTN) * 128; }

    f32x4 acc[4][4];
#pragma unroll
    for (int i = 0; i < 4; ++i)
#pragma unroll
        for (int j = 0; j < 4; ++j) acc[i][j] = (f32x4)0.f;

    const int lin_base = wv * 1024 + lane * 16;

    for (int k0 = 0; k0 < K; k0 += 64) {
        __syncthreads();
#pragma unroll
        for (int qc = 0; qc < 4; ++qc) {
            const int lin = qc * 4096 + lin_base;
            const int row = lin >> 7;
            const int c   = (lin >> 4) & 7;
            const int sc  = c ^ (row & 7);
            const size_t gofs  = (size_t)(bm + row) * K + k0 + sc * 8;
            const size_t gofsB = (size_t)(bn + row) * K + k0 + sc * 8;
            char* ldst  = (char*)As + qc * 4096 + wv * 1024;
            char* ldstB = (char*)Bs + qc * 4096 + wv * 1024;
            gload_lds16(A + gofs, ldst);
            gload_lds16(B + gofsB, ldstB);
        }
        asm volatile("s_waitcnt vmcnt(0)" ::: "memory");
        __syncthreads();
#pragma unroll
        for (int ks = 0; ks < 2; ++ks) {
            bf16x8 af[4], bfv[4];
            const int ca = ks * 4 + (lane >> 4);
#pragma unroll
            for (int f = 0; f < 4; ++f) {
                const int ra = wm * 64 + f * 16 + (lane & 15);
                af[f] = __builtin_bit_cast(bf16x8,
                    *(const s16x8*)((const char*)As + ra * 128 + ((ca ^ (ra & 7)) << 4)));
                const int rb = wn * 64 + f * 16 + (lane & 15);
                bfv[f] = __builtin_bit_cast(bf16x8,
                    *(const s16x8*)((const char*)Bs + rb * 128 + ((ca ^ (rb & 7)) << 4)));
            }
#pragma unroll
            for (int i = 0; i < 4; ++i)
#pragma unroll
                for (int j = 0; j < 4; ++j)
                    acc[i][j] = __builtin_amdgcn_mfma_f32_16x16x32_bf16(
                        af[i], bfv[j], acc[i][j], 0, 0, 0);
        }
    }

    const int col0 = bn + wn * 64 + (lane & 15);
    if (tmode == 0) {
        float bs[4];
#pragma unroll
        for (int j = 0; j < 4; ++j) {
            const int col = col0 + j * 16;
            bs[j] = b1[col];
            if (b2) bs[j] += b2[col];
        }

        if (part) {
            float pm[4][4], ps[4][4];
#pragma unroll
            for (int i = 0; i < 4; ++i)
#pragma unroll
                for (int rg = 0; rg < 4; ++rg) {
                    float m = acc[i][0][rg] + bs[0];
                    m = fmaxf(m, acc[i][1][rg] + bs[1]);
                    m = fmaxf(m, acc[i][2][rg] + bs[2]);
                    m = fmaxf(m, acc[i][3][rg] + bs[3]);
                    pm[i][rg] = m;
                }
#pragma unroll
            for (int mask = 1; mask <= 8; mask <<= 1)
#pragma unroll
                for (int i = 0; i < 4; ++i)
#pragma unroll
                    for (int rg = 0; rg < 4; ++rg)
                        pm[i][rg] = fmaxf(pm[i][rg], __shfl_xor(pm[i][rg], mask));
#pragma unroll
            for (int i = 0; i < 4; ++i)
#pragma unroll
                for (int rg = 0; rg < 4; ++rg) {
                    float s = 0.f;
#pragma unroll
                    for (int j = 0; j < 4; ++j)
                        s += expf(acc[i][j][rg] + bs[j] - pm[i][rg]);
                    ps[i][rg] = s;
                }
#pragma unroll
            for (int mask = 1; mask <= 8; mask <<= 1)
#pragma unroll
                for (int i = 0; i < 4; ++i)
#pragma unroll
                    for (int rg = 0; rg < 4; ++rg)
                        ps[i][rg] += __shfl_xor(ps[i][rg], mask);
            if ((lane & 15) == 0) {
#pragma unroll
                for (int i = 0; i < 4; ++i)
#pragma unroll
                    for (int rg = 0; rg < 4; ++rg) {
                        const int r64 = ((lane >> 4) << 2) + i * 16 + rg;
                        prt[wn][wm * 64 + r64][0] = pm[i][rg];
                        prt[wn][wm * 64 + r64][1] = ps[i][rg];
                    }
            }
            __syncthreads();
            if (tid < 128) {
                const float m0_ = prt[0][tid][0], s0_ = prt[0][tid][1];
                const float m1_ = prt[1][tid][0], s1_ = prt[1][tid][1];
                const float Mx = fmaxf(m0_, m1_);
                const float Sx = s0_ * expf(m0_ - Mx) + s1_ * expf(m1_ - Mx);
                const size_t o = ((size_t)(bm + tid) * nTN + (bn >> 7)) * 2;
                part[o] = Mx; part[o + 1] = Sx;
            }
        }

        // ---- LDS-staged coalesced C-write: two 64x128 halves, full-line float4 stores ----
        float* cst = (float*)smem;          // [64][132] fp32 (As/Bs dead)
        const int lr0 = (lane >> 4) << 2;
        const int lc0 = wn * 64 + (lane & 15);
#pragma unroll
        for (int h = 0; h < 2; ++h) {
            __syncthreads();
            if (wm == h) {
#pragma unroll
                for (int i = 0; i < 4; ++i)
#pragma unroll
                    for (int j = 0; j < 4; ++j)
#pragma unroll
                        for (int rg = 0; rg < 4; ++rg)
                            cst[(lr0 + i * 16 + rg) * 132 + lc0 + j * 16] = acc[i][j][rg] + bs[j];
            }
            __syncthreads();
#pragma unroll
            for (int k = 0; k < 8; ++k) {
                const int idx = tid + k * 256;
                const int rr = idx >> 5, c4 = idx & 31;
                const float4 v = *reinterpret_cast<const float4*>(&cst[rr * 132 + c4 * 4]);
                *reinterpret_cast<float4*>(&C[(size_t)(bm + h * 64 + rr) * N + bn + c4 * 4]) = v;
            }
        }
    } else {
        const int tblk = (bm >> 6) + wm;
        const int rb = (lane >> 4) << 2;
#pragma unroll
        for (int i = 0; i < 4; ++i) {
#pragma unroll
            for (int j = 0; j < 4; ++j) {
                const int col = col0 + j * 16;
                float bias = b1[col];
                if (b2) bias += b2[col];
                float4 v = { acc[i][j][0] + bias, acc[i][j][1] + bias,
                             acc[i][j][2] + bias, acc[i][j][3] + bias };
                *reinterpret_cast<float4*>(&C[((size_t)tblk * N + col) * 64 + rb + i * 16]) = v;
            }
        }
    }
}

// ---------------- persistent MFMA LSTM scan, WAVE-SCOPED producer polling (R14) ----------------
template<int H_T>
__global__ __launch_bounds__(256, 1) void lstm_mfma_scan(
    const float* __restrict__ xw0, const float* __restrict__ xw1,
    const float* __restrict__ Whh0, const float* __restrict__ Whh1,
    const unsigned short* __restrict__ h0b, const float* __restrict__ c0,
    unsigned short* __restrict__ hist,
    unsigned short* __restrict__ hsb, float* __restrict__ csd,
    int T, int ndir, int rev_mask, int* bar)
{
    constexpr int KST = H_T / 32;
    constexpr int CH  = H_T / 8;
    constexpr int CPW = CH / 4;
    constexpr int NB  = CPW / 8;

    __shared__ __align__(16) unsigned short h_lds[64 * H_T];
    __shared__ float pre[64][17];
    __shared__ __align__(8) unsigned short hpack[64][4];

    const int tid  = threadIdx.x;
    const int lane = tid & 63;
    const int w    = tid >> 6;
    const int bpd  = (ndir == 2) ? 128 : 256;
    const int dir  = blockIdx.x / bpd;
    const int blk  = blockIdx.x - dir * bpd;
    const int m0   = blk * 4;
    const int rev  = (rev_mask >> dir) & 1;
    const float* xw  = dir ? xw1  : xw0;
    const float* Whh = dir ? Whh1 : Whh0;
    const int dcol = dir * H_T;
    const int b = tid & 63;
    const int j = tid >> 6;

    int* myflag = bar + blockIdx.x * 32;
    const int* pflag = bar + (dir * bpd + w * 2 * CPW + (lane % (2 * CPW))) * 32;
    const int scc = w * CPW + (lane % CPW);
    const int sr0 = (lane / CPW) * CPW;

    const int n  = lane & 15;
    const int kg = lane >> 4;
    const int wr = (n >> 2) * H_T + m0 + (n & 3);
    s16x8 wfr[KST];
#pragma unroll
    for (int ks = 0; ks < KST; ++ks) {
        const float* wp = Whh + (size_t)wr * H_T + ks * 32 + kg * 8;
        const float4 lo = *reinterpret_cast<const float4*>(wp);
        const float4 hi = *reinterpret_cast<const float4*>(wp + 4);
        s16x8 rr;
        rr[0] = (short)f2bf(lo.x); rr[1] = (short)f2bf(lo.y);
        rr[2] = (short)f2bf(lo.z); rr[3] = (short)f2bf(lo.w);
        rr[4] = (short)f2bf(hi.x); rr[5] = (short)f2bf(hi.y);
        rr[6] = (short)f2bf(hi.z); rr[7] = (short)f2bf(hi.w);
        wfr[ks] = rr;
    }

    float c  = c0 ? c0[(size_t)b * HSTR + dcol + m0 + j] : 0.f;
    float hn = 0.f;
    const int rA  = w * 16 + n;
    const int rAx = rA & 7;

    for (int s = 0; s < T; ++s) {
        const int tt = rev ? (T - 1 - s) : s;

        const float* xb = xw + ((size_t)tt * 4096 + m0 + j) * 64 + b;
        float xg0 = g_load1(xb);
        float xg1 = g_load1(xb + (size_t)H_T * 64);
        float xg2 = g_load1(xb + (size_t)2 * H_T * 64);
        float xg3 = g_load1(xb + (size_t)3 * H_T * 64);

        if (s > 0) {
            for (;;) {
                const int f = sc_load1(pflag);
                if (__all(f >= s)) break;
            }
        }

        const unsigned short* hb;
        size_t tofs;
        if (s == 0) { hb = h0b; tofs = 0; }
        else {
            const int tp = rev ? (tt + 1) : (tt - 1);
            hb = hist; tofs = (size_t)tp * (64 * 1024);
        }

        float p0 = 0.f, p1 = 0.f, p2 = 0.f, p3 = 0.f;
        if (hb) {
            const unsigned short* src = hb + tofs + dcol + scc * 8;
            f4_t bufA[8], bufB[8];
            auto issue = [&](f4_t (&bf)[8], int bt) {
#pragma unroll
                for (int jj = 0; jj < 8; ++jj) {
                    const int rr_ = sr0 + bt * 8 + jj;
                    bf[jj] = sc_load4(src + (size_t)rr_ * 1024);
                }
            };
            auto writeb = [&](const f4_t (&bf)[8], int bt) {
#pragma unroll
                for (int jj = 0; jj < 8; ++jj) {
                    const int rr_ = sr0 + bt * 8 + jj;
                    const int off = rr_ * (2 * H_T) + ((scc ^ (rr_ & 7)) << 4);
                    *(f4_t*)((char*)h_lds + off) = bf[jj];
                }
            };
            issue(bufA, 0);
            if (NB > 1) issue(bufB, 1);
#pragma unroll
            for (int bt = 0; bt < NB; ++bt) {
                if (bt + 1 < NB) wait_vm8(); else wait_vm0();
                if (bt & 1) writeb(bufB, bt); else writeb(bufA, bt);
                if (bt + 2 < NB) { if (bt & 1) issue(bufB, bt + 2); else issue(bufA, bt + 2); }
            }
            __syncthreads();

            f32x4 acc = {0.f, 0.f, 0.f, 0.f};
#pragma unroll
            for (int ks = 0; ks < KST; ++ks) {
                const int cc_ = ks * 4 + kg;
                const int off = rA * (2 * H_T) + ((cc_ ^ rAx) << 4);
                const bf16x8 a = __builtin_bit_cast(bf16x8,
                    *(const s16x8*)((const char*)h_lds + off));
                acc = __builtin_amdgcn_mfma_f32_16x16x32_bf16(
                    a, __builtin_bit_cast(bf16x8, wfr[ks]), acc, 0, 0, 0);
            }
#pragma unroll
            for (int rg = 0; rg < 4; ++rg)
                pre[w * 16 + kg * 4 + rg][n] = acc[rg];
            __syncthreads();
            p0 = pre[b][0 + j]; p1 = pre[b][4 + j];
            p2 = pre[b][8 + j]; p3 = pre[b][12 + j];
        }

        asm volatile("s_waitcnt vmcnt(0)"
                     : "+v"(xg0), "+v"(xg1), "+v"(xg2), "+v"(xg3) :: "memory");

        const float ig = sigmoidf_(p0 + xg0);
        const float fg = sigmoidf_(p1 + xg1);
        const float gg = tanhf(p2 + xg2);
        const float og = sigmoidf_(p3 + xg3);
        c  = fg * c + ig * gg;
        hn = og * tanhf(c);

        hpack[b][j] = f2bf(hn);
        __syncthreads();
        if (tid < 64) {
            const i32x2 v2 = *reinterpret_cast<const i32x2*>(&hpack[tid][0]);
            sc_store8(hist + (size_t)tt * (64 * 1024) + (size_t)tid * 1024 + dcol + m0, v2);
        }
        wait_vm0();
        if (s + 1 < T && tid == 0) sc_store_int(myflag, s + 1);
    }

    if (hsb) hsb[(size_t)b * 1024 + dcol + m0 + j] = f2bf(hn);
    if (csd) csd[(size_t)b * HSTR + dcol + m0 + j] = c;
}

// ---------------- log-softmax: merge partials + normalize, one kernel ----------------
__global__ __launch_bounds__(256) void lsm_norm_kernel(
    float* __restrict__ x, const float* __restrict__ part, int nt, int n4)
{
    __shared__ float ms[256], ss[256];
    const int tid = threadIdx.x;
    float m = -3.0e38f, s = 0.f;
    for (int t = tid; t < nt; t += 256) {
        const float mo = part[((size_t)blockIdx.x * nt + t) * 2];
        const float so = part[((size_t)blockIdx.x * nt + t) * 2 + 1];
        const float M = fmaxf(m, mo);
        s = s * expf(m - M) + so * expf(mo - M);
        m = M;
    }
    ms[tid] = m; ss[tid] = s;
    __syncthreads();
    for (int off = 128; off > 0; off >>= 1) {
        if (tid < off) {
            const float m2 = ms[tid + off], s2 = ss[tid + off];
            const float m1 = ms[tid],       s1 = ss[tid];
            const float M = fmaxf(m1, m2);
            ss[tid] = s1 * expf(m1 - M) + s2 * expf(m2 - M);
            ms[tid] = M;
        }
        __syncthreads();
    }
    const float ML = ms[0] + logf(ss[0]);
    float4* p = reinterpret_cast<float4*>(x + (size_t)blockIdx.x * (n4 * 4));
    for (int cc = tid; cc < n4; cc += 256) {
        float4 v = p[cc];
        v.x -= ML; v.y -= ML; v.z -= ML; v.w -= ML;
        p[cc] = v;
    }
}

// ---------------- host-side orchestration ----------------
extern "C" void kernel_launch(void* const* d_in, const int* in_sizes, int n_in,
                              void* d_out, int out_size, void* d_ws, size_t ws_size,
                              hipStream_t stream)
{
    const int*   sent  = (const int*)d_in[0];
    const int*   targ  = (const int*)d_in[1];
    const float* emb   = (const float*)d_in[2];
    const float* e0Wih = (const float*)d_in[3];
    const float* e0Whh = (const float*)d_in[4];
    const float* e0bih = (const float*)d_in[5];
    const float* e0bhh = (const float*)d_in[6];
    const float* e1Wih = (const float*)d_in[7];
    const float* e1Whh = (const float*)d_in[8];
    const float* e1bih = (const float*)d_in[9];
    const float* e1bhh = (const float*)d_in[10];
    const float* d0Wih = (const float*)d_in[11];
    const float* d0Whh = (const float*)d_in[12];
    const float* d0bih = (const float*)d_in[13];
    const float* d0bhh = (const float*)d_in[14];
    const float* d1Wih = (const float*)d_in[15];
    const float* d1Whh = (const float*)d_in[16];
    const float* d1bih = (const float*)d_in[17];
    const float* d1bhh = (const float*)d_in[18];
    const float* Wout  = (const float*)d_in[19];
    const float* bout  = (const float*)d_in[20];

    float* ws  = (float*)d_ws;
    float* xwA = ws + WS_XWA;
    float* xwB = ws + WS_XWB;
    float* cs  = ws + WS_CS;
    int*   bar = (int*)(ws + WS_BAR);
    unsigned short* ub    = (unsigned short*)(ws + WS_BF);
    unsigned short* x0b   = ub + U_X0B;
    unsigned short* h_e0  = ub + U_HE0;
    unsigned short* h_e1  = ub + U_HE1;
    unsigned short* h_d0  = ub + U_HD0;
    unsigned short* h_d1  = ub + U_HD1;
    unsigned short* hsb   = ub + U_HSB;
    unsigned short* e0Wb  = ub + U_E0W;
    unsigned short* e1Wb  = ub + U_E1W;
    unsigned short* d0Wb  = ub + U_D0W;
    unsigned short* d1Wb  = ub + U_D1W;
    unsigned short* Woutb = (unsigned short*)xwA;
    float* out = (float*)d_out;

    hipMemsetAsync(bar, 0, 4 * 8192 * sizeof(int), stream);

    // ---- weight conversions (fp32 -> bf16), one kernel ----
    f2b_multi_kernel<<<1280, 256, 0, stream>>>(e0Wih, e0Wb, e1Wih, e1Wb,
                                               d0Wih, d0Wb, d1Wih, d1Wb);

    // ---- encoder layer 0 (both dirs in ONE GEMM: N=4096, dir1 cols at 2048) ----
    embed_src_kernel<<<(S_LEN * BSZ) / 4, 256, 0, stream>>>(sent, emb, x0b);
    gemm_bf16_kernel<<<64 * 32, 256, 0, stream>>>(x0b, e0Wb, e0bih, e0bhh, xwA,
                                                  S_LEN * BSZ, 4096, EMBD, 32, 1, nullptr);
    lstm_mfma_scan<512><<<256, 256, 0, stream>>>(xwA, xwA + 2048 * 64,
                                                 e0Whh, e0Whh + 2048ull * 512,
                                                 nullptr, nullptr, h_e0,
                                                 hsb, cs, S_LEN, 2, 2, bar);
    // ---- encoder layer 1 (final states only) ----
    gemm_bf16_kernel<<<64 * 32, 256, 0, stream>>>(h_e0, e1Wb, e1bih, e1bhh, xwA,
                                                  S_LEN * BSZ, 4096, 2 * HID_, 32, 1, nullptr);
    lstm_mfma_scan<512><<<256, 256, 0, stream>>>(xwA, xwA + 2048 * 64,
                                                 e1Whh, e1Whh + 2048ull * 512,
                                                 nullptr, nullptr, h_e1,
                                                 hsb + 65536, cs + 65536,
                                                 S_LEN, 2, 2, bar + 8192);
    // ---- decoder layer 0 ----
    embed_dec_kernel<<<(T_LEN * BSZ) / 4, 256, 0, stream>>>(sent, targ, emb, x0b);
    gemm_bf16_kernel<<<32 * 32, 256, 0, stream>>>(x0b, d0Wb, d0bih, d0bhh, xwA,
                                                  T_LEN * BSZ, 4 * DHID_, EMBD, 32, 1, nullptr);
    lstm_mfma_scan<1024><<<256, 256, 0, stream>>>(xwA, nullptr, d0Whh, nullptr,
                                                  hsb, cs, h_d0,
                                                  nullptr, nullptr, T_LEN, 1, 0,
                                                  bar + 2 * 8192);
    // ---- Wout -> bf16 (xwA region free after dec0 scan) ----
    f2b_kernel<<<2048, 256, 0, stream>>>(Wout, Woutb, (VOC_ * DHID_) / 4);
    // ---- decoder layer 1 ----
    gemm_bf16_kernel<<<32 * 32, 256, 0, stream>>>(h_d0, d1Wb, d1bih, d1bhh, xwB,
                                                  T_LEN * BSZ, 4 * DHID_, DHID_, 32, 1, nullptr);
    lstm_mfma_scan<1024><<<256, 256, 0, stream>>>(xwB, nullptr, d1Whh, nullptr,
                                                  hsb + 65536, cs + 65536, h_d1,
                                                  nullptr, nullptr, T_LEN, 1, 0,
                                                  bar + 3 * 8192);
    // ---- vocab projection (fused softmax partials) + merge+normalize ----
    gemm_bf16_kernel<<<32 * 250, 256, 0, stream>>>(h_d1, Woutb, bout, nullptr, out,
                                                   T_LEN * BSZ, VOC_, DHID_, 250, 0, xwB);
    lsm_norm_kernel<<<T_LEN * BSZ, 256, 0, stream>>>(out, xwB, 250, VOC_ / 4);
}

// Round 16
// 2650.251 us; speedup vs baseline: 1.0008x; 1.0008x over previous
//
#include <hip/hip_runtime.h>

#define S_LEN 128
#define T_LEN 64
#define BSZ   64
#define EMBD  256
#define HID_  512
#define DHID_ 1024
#define VOC_  32000
#define HSTR  1024

typedef float  f4_t  __attribute__((ext_vector_type(4)));
typedef float  f32x4 __attribute__((ext_vector_type(4)));
typedef short  s16x8 __attribute__((ext_vector_type(8)));
typedef __bf16 bf16x8 __attribute__((ext_vector_type(8)));
typedef unsigned short u16x4 __attribute__((ext_vector_type(4)));
typedef int    i32x2 __attribute__((ext_vector_type(2)));

// ---------------- workspace layout ----------------
// float offsets:
#define WS_XWA  0ull
#define WS_XWB  (WS_XWA + 16777216ull)
#define WS_CS   (WS_XWB + 16777216ull)
#define WS_BAR  (WS_CS  + 131072ull)
#define WS_BF   (WS_BAR + 32768ull)
// ushort offsets within bf16 region:
#define U_X0B   0ull
#define U_HE0   (U_X0B + 2097152ull)
#define U_HE1   (U_HE0 + 8388608ull)
#define U_HD0   (U_HE1 + 8388608ull)
#define U_HD1   (U_HD0 + 4194304ull)
#define U_HSB   (U_HD1 + 4194304ull)
#define U_E0W   (U_HSB + 131072ull)
#define U_E1W   (U_E0W + 1048576ull)
#define U_D0W   (U_E1W + 4194304ull)
#define U_D1W   (U_D0W + 1048576ull)

__device__ __forceinline__ unsigned short f2bf(float x) {
    unsigned u = __builtin_bit_cast(unsigned, x);
    return (unsigned short)((u + 0x7fffu + ((u >> 16) & 1u)) >> 16);
}

// ---------------- coherent (LLC-scope) memory helpers ----------------
__device__ __forceinline__ f4_t sc_load4(const void* p) {
    f4_t v;
    asm volatile("global_load_dwordx4 %0, %1, off sc0 sc1" : "=v"(v) : "v"(p));
    return v;                               // NOT ready until a vmcnt wait
}
__device__ __forceinline__ int sc_load1(const int* p) {
    int v;
    asm volatile("global_load_dword %0, %1, off sc0 sc1\n\ts_waitcnt vmcnt(0)"
                 : "=v"(v) : "v"(p) : "memory");
    return v;
}
__device__ __forceinline__ void sc_store_int(int* p, int v) {
    asm volatile("global_store_dword %0, %1, off sc0 sc1" :: "v"(p), "v"(v) : "memory");
}
__device__ __forceinline__ void sc_store8(void* p, i32x2 v) {
    asm volatile("global_store_dwordx2 %0, %1, off sc0 sc1" :: "v"(p), "v"(v) : "memory");
}
__device__ __forceinline__ float g_load1(const float* p) {   // plain cached load, no wait
    float v;
    asm volatile("global_load_dword %0, %1, off" : "=v"(v) : "v"(p));
    return v;
}
__device__ __forceinline__ void wait_vm0() {
    asm volatile("s_waitcnt vmcnt(0)" ::: "memory");
}
__device__ __forceinline__ void wait_vm8() {
    asm volatile("s_waitcnt vmcnt(8)" ::: "memory");
}

__device__ __forceinline__ void gload_lds16(const void* g, void* l) {
    __builtin_amdgcn_global_load_lds(
        (const __attribute__((address_space(1))) void*)g,
        (__attribute__((address_space(3))) void*)l, 16, 0, 0);
}

__device__ __forceinline__ float sigmoidf_(float x) { return 1.f / (1.f + expf(-x)); }

// ---------------- fp32 -> bf16 conversion (single kernel, 4 weight segments) ----------------
__global__ __launch_bounds__(256) void f2b_multi_kernel(
    const float* __restrict__ p0, unsigned short* __restrict__ q0,
    const float* __restrict__ p1, unsigned short* __restrict__ q1,
    const float* __restrict__ p2, unsigned short* __restrict__ q2,
    const float* __restrict__ p3, unsigned short* __restrict__ q3)
{
    const int stride = gridDim.x * 256;
    for (int i = blockIdx.x * 256 + threadIdx.x; i < 2621440; i += stride) {
        const float* in; unsigned short* out; int o;
        if (i < 262144)       { in = p0; out = q0; o = i; }
        else if (i < 1310720) { in = p1; out = q1; o = i - 262144; }
        else if (i < 1572864) { in = p2; out = q2; o = i - 1310720; }
        else                  { in = p3; out = q3; o = i - 1572864; }
        const float4 v = reinterpret_cast<const float4*>(in)[o];
        u16x4 w = { f2bf(v.x), f2bf(v.y), f2bf(v.z), f2bf(v.w) };
        reinterpret_cast<u16x4*>(out)[o] = w;
    }
}

__global__ __launch_bounds__(256) void f2b_kernel(
    const float* __restrict__ in, unsigned short* __restrict__ out, int n4)
{
    const int stride = gridDim.x * 256;
    for (int i = blockIdx.x * 256 + threadIdx.x; i < n4; i += stride) {
        const float4 v = reinterpret_cast<const float4*>(in)[i];
        u16x4 o = { f2bf(v.x), f2bf(v.y), f2bf(v.z), f2bf(v.w) };
        reinterpret_cast<u16x4*>(out)[i] = o;
    }
}

// ---------------- embedding gathers (emit bf16), 4 tokens per 256-thr block ----------------
__global__ __launch_bounds__(256) void embed_src_kernel(
    const int* __restrict__ toks, const float* __restrict__ emb,
    unsigned short* __restrict__ out)
{
    const int i = blockIdx.x * 4 + (threadIdx.x >> 6);
    const int lane = threadIdx.x & 63;
    const int tok = toks[i];
    const float4 v = reinterpret_cast<const float4*>(emb + (size_t)tok * EMBD)[lane];
    u16x4 o = { f2bf(v.x), f2bf(v.y), f2bf(v.z), f2bf(v.w) };
    reinterpret_cast<u16x4*>(out + (size_t)i * EMBD)[lane] = o;
}

__global__ __launch_bounds__(256) void embed_dec_kernel(
    const int* __restrict__ sent, const int* __restrict__ targ,
    const float* __restrict__ emb, unsigned short* __restrict__ out)
{
    const int i = blockIdx.x * 4 + (threadIdx.x >> 6);
    const int lane = threadIdx.x & 63;
    const int t = i >> 6, b = i & 63;
    const int tok = (t == 0) ? sent[(S_LEN - 1) * BSZ + b] : targ[(t - 1) * BSZ + b];
    const float4 v = reinterpret_cast<const float4*>(emb + (size_t)tok * EMBD)[lane];
    u16x4 o = { f2bf(v.x), f2bf(v.y), f2bf(v.z), f2bf(v.w) };
    reinterpret_cast<u16x4*>(out + (size_t)i * EMBD)[lane] = o;
}

// ---------------- bf16 MFMA GEMM (tmode1): C fp32 as (M/64, N, 64) = (T,N,B) ----------------
__global__ __launch_bounds__(256) void gemm_bf16_kernel(
    const unsigned short* __restrict__ A, const unsigned short* __restrict__ B,
    const float* __restrict__ b1, const float* __restrict__ b2,
    float* __restrict__ C, int M, int N, int K, int nTN)
{
    __shared__ __align__(16) unsigned short As[128 * 64];
    __shared__ __align__(16) unsigned short Bs[128 * 64];

    const int tid  = threadIdx.x;
    const int lane = tid & 63;
    const int wv   = tid >> 6;
    const int wm   = wv >> 1, wn = wv & 1;

    const int nwg = gridDim.x;
    const int q = nwg >> 3, r = nwg & 7;
    const int xcd = blockIdx.x & 7, io = blockIdx.x >> 3;
    const int wg = (xcd < r ? xcd * (q + 1) : r * (q + 1) + (xcd - r) * q) + io;
    const int bm = (wg / nTN) * 128;
    const int bn = (wg % nTN) * 128;

    f32x4 acc[4][4];
#pragma unroll
    for (int i = 0; i < 4; ++i)
#pragma unroll
        for (int j = 0; j < 4; ++j) acc[i][j] = (f32x4)0.f;

    const int lin_base = wv * 1024 + lane * 16;

    for (int k0 = 0; k0 < K; k0 += 64) {
        __syncthreads();
#pragma unroll
        for (int qc = 0; qc < 4; ++qc) {
            const int lin = qc * 4096 + lin_base;
            const int row = lin >> 7;
            const int c   = (lin >> 4) & 7;
            const int sc  = c ^ (row & 7);
            const size_t gofs  = (size_t)(bm + row) * K + k0 + sc * 8;
            const size_t gofsB = (size_t)(bn + row) * K + k0 + sc * 8;
            char* ldst  = (char*)As + qc * 4096 + wv * 1024;
            char* ldstB = (char*)Bs + qc * 4096 + wv * 1024;
            gload_lds16(A + gofs, ldst);
            gload_lds16(B + gofsB, ldstB);
        }
        asm volatile("s_waitcnt vmcnt(0)" ::: "memory");
        __syncthreads();
#pragma unroll
        for (int ks = 0; ks < 2; ++ks) {
            bf16x8 af[4], bfv[4];
            const int ca = ks * 4 + (lane >> 4);
#pragma unroll
            for (int f = 0; f < 4; ++f) {
                const int ra = wm * 64 + f * 16 + (lane & 15);
                af[f] = __builtin_bit_cast(bf16x8,
                    *(const s16x8*)((const char*)As + ra * 128 + ((ca ^ (ra & 7)) << 4)));
                const int rb = wn * 64 + f * 16 + (lane & 15);
                bfv[f] = __builtin_bit_cast(bf16x8,
                    *(const s16x8*)((const char*)Bs + rb * 128 + ((ca ^ (rb & 7)) << 4)));
            }
#pragma unroll
            for (int i = 0; i < 4; ++i)
#pragma unroll
                for (int j = 0; j < 4; ++j)
                    acc[i][j] = __builtin_amdgcn_mfma_f32_16x16x32_bf16(
                        af[i], bfv[j], acc[i][j], 0, 0, 0);
        }
    }

    const int col0 = bn + wn * 64 + (lane & 15);
    const int tblk = (bm >> 6) + wm;
    const int rb = (lane >> 4) << 2;
#pragma unroll
    for (int i = 0; i < 4; ++i) {
#pragma unroll
        for (int j = 0; j < 4; ++j) {
            const int col = col0 + j * 16;
            float bias = b1[col];
            if (b2) bias += b2[col];
            float4 v = { acc[i][j][0] + bias, acc[i][j][1] + bias,
                         acc[i][j][2] + bias, acc[i][j][3] + bias };
            *reinterpret_cast<float4*>(&C[((size_t)tblk * N + col) * 64 + rb + i * 16]) = v;
        }
    }
}

// ---------------- logits GEMM: 128x256 tile, fused softmax partials ----------------
// C fp32 row-major (M,N); per-wave 64x128 sub-tile => each wave owns ONE 128-col
// partials tile (no LDS combine). part[(row*250 + tile)*2 + {0,1}] = (max, sumexp).
__global__ __launch_bounds__(256) void gemm_logits_kernel(
    const unsigned short* __restrict__ A, const unsigned short* __restrict__ B,
    const float* __restrict__ b1,
    float* __restrict__ C, int M, int N, int K,
    float* __restrict__ part)
{
    __shared__ __align__(16) unsigned short As[128 * 64];   // 16 KB
    __shared__ __align__(16) unsigned short Bs[256 * 64];   // 32 KB

    const int tid  = threadIdx.x;
    const int lane = tid & 63;
    const int wv   = tid >> 6;
    const int wm   = wv >> 1, wn = wv & 1;

    const int nwg = gridDim.x;                // 32*125 = 4000
    const int q = nwg >> 3, r = nwg & 7;
    const int xcd = blockIdx.x & 7, io = blockIdx.x >> 3;
    const int wg = (xcd < r ? xcd * (q + 1) : r * (q + 1) + (xcd - r) * q) + io;
    const int bm = (wg / 125) * 128;          // m-major: A-tile L2-hot
    const int bn = (wg % 125) * 256;

    f32x4 acc[4][8];
#pragma unroll
    for (int i = 0; i < 4; ++i)
#pragma unroll
        for (int j = 0; j < 8; ++j) acc[i][j] = (f32x4)0.f;

    const int lin_base = wv * 1024 + lane * 16;

    for (int k0 = 0; k0 < K; k0 += 64) {
        __syncthreads();
#pragma unroll
        for (int qc = 0; qc < 4; ++qc) {       // A: 16 KB
            const int lin = qc * 4096 + lin_base;
            const int row = lin >> 7;
            const int c   = (lin >> 4) & 7;
            const int sc  = c ^ (row & 7);
            gload_lds16(A + (size_t)(bm + row) * K + k0 + sc * 8,
                        (char*)As + qc * 4096 + wv * 1024);
        }
#pragma unroll
        for (int qc = 0; qc < 8; ++qc) {       // B: 32 KB
            const int lin = qc * 4096 + lin_base;
            const int row = lin >> 7;
            const int c   = (lin >> 4) & 7;
            const int sc  = c ^ (row & 7);
            gload_lds16(B + (size_t)(bn + row) * K + k0 + sc * 8,
                        (char*)Bs + qc * 4096 + wv * 1024);
        }
        asm volatile("s_waitcnt vmcnt(0)" ::: "memory");
        __syncthreads();
#pragma unroll
        for (int ks = 0; ks < 2; ++ks) {
            bf16x8 af[4], bfv[8];
            const int ca = ks * 4 + (lane >> 4);
#pragma unroll
            for (int f = 0; f < 4; ++f) {
                const int ra = wm * 64 + f * 16 + (lane & 15);
                af[f] = __builtin_bit_cast(bf16x8,
                    *(const s16x8*)((const char*)As + ra * 128 + ((ca ^ (ra & 7)) << 4)));
            }
#pragma unroll
            for (int f = 0; f < 8; ++f) {
                const int rbq = wn * 128 + f * 16 + (lane & 15);
                bfv[f] = __builtin_bit_cast(bf16x8,
                    *(const s16x8*)((const char*)Bs + rbq * 128 + ((ca ^ (rbq & 7)) << 4)));
            }
#pragma unroll
            for (int i = 0; i < 4; ++i)
#pragma unroll
                for (int j = 0; j < 8; ++j)
                    acc[i][j] = __builtin_amdgcn_mfma_f32_16x16x32_bf16(
                        af[i], bfv[j], acc[i][j], 0, 0, 0);
        }
    }

    const int col0 = bn + wn * 128 + (lane & 15);
    const int row0 = bm + wm * 64 + ((lane >> 4) << 2);
    float bs[8];
#pragma unroll
    for (int j = 0; j < 8; ++j) bs[j] = b1[col0 + j * 16];

    // C stores (scattered float4-of-rows pattern as R14: 4B stores per col element)
#pragma unroll
    for (int i = 0; i < 4; ++i)
#pragma unroll
        for (int j = 0; j < 8; ++j)
#pragma unroll
            for (int rg = 0; rg < 4; ++rg)
                C[(size_t)(row0 + i * 16 + rg) * N + col0 + j * 16] = acc[i][j][rg] + bs[j];

    // per-wave softmax partials over this wave's 128 cols (one col-tile)
    float pm[4][4], ps[4][4];
#pragma unroll
    for (int i = 0; i < 4; ++i)
#pragma unroll
        for (int rg = 0; rg < 4; ++rg) {
            float m = acc[i][0][rg] + bs[0];
#pragma unroll
            for (int j = 1; j < 8; ++j) m = fmaxf(m, acc[i][j][rg] + bs[j]);
            pm[i][rg] = m;
        }
#pragma unroll
    for (int mask = 1; mask <= 8; mask <<= 1)
#pragma unroll
        for (int i = 0; i < 4; ++i)
#pragma unroll
            for (int rg = 0; rg < 4; ++rg)
                pm[i][rg] = fmaxf(pm[i][rg], __shfl_xor(pm[i][rg], mask));
#pragma unroll
    for (int i = 0; i < 4; ++i)
#pragma unroll
        for (int rg = 0; rg < 4; ++rg) {
            float s = 0.f;
#pragma unroll
            for (int j = 0; j < 8; ++j)
                s += expf(acc[i][j][rg] + bs[j] - pm[i][rg]);
            ps[i][rg] = s;
        }
#pragma unroll
    for (int mask = 1; mask <= 8; mask <<= 1)
#pragma unroll
        for (int i = 0; i < 4; ++i)
#pragma unroll
            for (int rg = 0; rg < 4; ++rg)
                ps[i][rg] += __shfl_xor(ps[i][rg], mask);
    if ((lane & 15) == 0) {
        const int tile = (bn >> 7) + wn;
#pragma unroll
        for (int i = 0; i < 4; ++i)
#pragma unroll
            for (int rg = 0; rg < 4; ++rg) {
                const size_t o = ((size_t)(row0 + i * 16 + rg) * 250 + tile) * 2;
                part[o] = pm[i][rg]; part[o + 1] = ps[i][rg];
            }
    }
}

// ---------------- persistent MFMA LSTM scan, WAVE-SCOPED producer polling (R14) ----------------
template<int H_T>
__global__ __launch_bounds__(256, 1) void lstm_mfma_scan(
    const float* __restrict__ xw0, const float* __restrict__ xw1,
    const float* __restrict__ Whh0, const float* __restrict__ Whh1,
    const unsigned short* __restrict__ h0b, const float* __restrict__ c0,
    unsigned short* __restrict__ hist,
    unsigned short* __restrict__ hsb, float* __restrict__ csd,
    int T, int ndir, int rev_mask, int* bar)
{
    constexpr int KST = H_T / 32;
    constexpr int CH  = H_T / 8;
    constexpr int CPW = CH / 4;
    constexpr int NB  = CPW / 8;

    __shared__ __align__(16) unsigned short h_lds[64 * H_T];
    __shared__ float pre[64][17];
    __shared__ __align__(8) unsigned short hpack[64][4];

    const int tid  = threadIdx.x;
    const int lane = tid & 63;
    const int w    = tid >> 6;
    const int bpd  = (ndir == 2) ? 128 : 256;
    const int dir  = blockIdx.x / bpd;
    const int blk  = blockIdx.x - dir * bpd;
    const int m0   = blk * 4;
    const int rev  = (rev_mask >> dir) & 1;
    const float* xw  = dir ? xw1  : xw0;
    const float* Whh = dir ? Whh1 : Whh0;
    const int dcol = dir * H_T;
    const int b = tid & 63;
    const int j = tid >> 6;

    int* myflag = bar + blockIdx.x * 32;
    const int* pflag = bar + (dir * bpd + w * 2 * CPW + (lane % (2 * CPW))) * 32;
    const int scc = w * CPW + (lane % CPW);
    const int sr0 = (lane / CPW) * CPW;

    const int n  = lane & 15;
    const int kg = lane >> 4;
    const int wr = (n >> 2) * H_T + m0 + (n & 3);
    s16x8 wfr[KST];
#pragma unroll
    for (int ks = 0; ks < KST; ++ks) {
        const float* wp = Whh + (size_t)wr * H_T + ks * 32 + kg * 8;
        const float4 lo = *reinterpret_cast<const float4*>(wp);
        const float4 hi = *reinterpret_cast<const float4*>(wp + 4);
        s16x8 rr;
        rr[0] = (short)f2bf(lo.x); rr[1] = (short)f2bf(lo.y);
        rr[2] = (short)f2bf(lo.z); rr[3] = (short)f2bf(lo.w);
        rr[4] = (short)f2bf(hi.x); rr[5] = (short)f2bf(hi.y);
        rr[6] = (short)f2bf(hi.z); rr[7] = (short)f2bf(hi.w);
        wfr[ks] = rr;
    }

    float c  = c0 ? c0[(size_t)b * HSTR + dcol + m0 + j] : 0.f;
    float hn = 0.f;
    const int rA  = w * 16 + n;
    const int rAx = rA & 7;

    for (int s = 0; s < T; ++s) {
        const int tt = rev ? (T - 1 - s) : s;

        const float* xb = xw + ((size_t)tt * 4096 + m0 + j) * 64 + b;
        float xg0 = g_load1(xb);
        float xg1 = g_load1(xb + (size_t)H_T * 64);
        float xg2 = g_load1(xb + (size_t)2 * H_T * 64);
        float xg3 = g_load1(xb + (size_t)3 * H_T * 64);

        if (s > 0) {
            for (;;) {
                const int f = sc_load1(pflag);
                if (__all(f >= s)) break;
            }
        }

        const unsigned short* hb;
        size_t tofs;
        if (s == 0) { hb = h0b; tofs = 0; }
        else {
            const int tp = rev ? (tt + 1) : (tt - 1);
            hb = hist; tofs = (size_t)tp * (64 * 1024);
        }

        float p0 = 0.f, p1 = 0.f, p2 = 0.f, p3 = 0.f;
        if (hb) {
            const unsigned short* src = hb + tofs + dcol + scc * 8;
            f4_t bufA[8], bufB[8];
            auto issue = [&](f4_t (&bf)[8], int bt) {
#pragma unroll
                for (int jj = 0; jj < 8; ++jj) {
                    const int rr_ = sr0 + bt * 8 + jj;
                    bf[jj] = sc_load4(src + (size_t)rr_ * 1024);
                }
            };
            auto writeb = [&](const f4_t (&bf)[8], int bt) {
#pragma unroll
                for (int jj = 0; jj < 8; ++jj) {
                    const int rr_ = sr0 + bt * 8 + jj;
                    const int off = rr_ * (2 * H_T) + ((scc ^ (rr_ & 7)) << 4);
                    *(f4_t*)((char*)h_lds + off) = bf[jj];
                }
            };
            issue(bufA, 0);
            if (NB > 1) issue(bufB, 1);
#pragma unroll
            for (int bt = 0; bt < NB; ++bt) {
                if (bt + 1 < NB) wait_vm8(); else wait_vm0();
                if (bt & 1) writeb(bufB, bt); else writeb(bufA, bt);
                if (bt + 2 < NB) { if (bt & 1) issue(bufB, bt + 2); else issue(bufA, bt + 2); }
            }
            __syncthreads();

            f32x4 acc = {0.f, 0.f, 0.f, 0.f};
#pragma unroll
            for (int ks = 0; ks < KST; ++ks) {
                const int cc_ = ks * 4 + kg;
                const int off = rA * (2 * H_T) + ((cc_ ^ rAx) << 4);
                const bf16x8 a = __builtin_bit_cast(bf16x8,
                    *(const s16x8*)((const char*)h_lds + off));
                acc = __builtin_amdgcn_mfma_f32_16x16x32_bf16(
                    a, __builtin_bit_cast(bf16x8, wfr[ks]), acc, 0, 0, 0);
            }
#pragma unroll
            for (int rg = 0; rg < 4; ++rg)
                pre[w * 16 + kg * 4 + rg][n] = acc[rg];
            __syncthreads();
            p0 = pre[b][0 + j]; p1 = pre[b][4 + j];
            p2 = pre[b][8 + j]; p3 = pre[b][12 + j];
        }

        asm volatile("s_waitcnt vmcnt(0)"
                     : "+v"(xg0), "+v"(xg1), "+v"(xg2), "+v"(xg3) :: "memory");

        const float ig = sigmoidf_(p0 + xg0);
        const float fg = sigmoidf_(p1 + xg1);
        const float gg = tanhf(p2 + xg2);
        const float og = sigmoidf_(p3 + xg3);
        c  = fg * c + ig * gg;
        hn = og * tanhf(c);

        hpack[b][j] = f2bf(hn);
        __syncthreads();
        if (tid < 64) {
            const i32x2 v2 = *reinterpret_cast<const i32x2*>(&hpack[tid][0]);
            sc_store8(hist + (size_t)tt * (64 * 1024) + (size_t)tid * 1024 + dcol + m0, v2);
        }
        wait_vm0();
        if (s + 1 < T && tid == 0) sc_store_int(myflag, s + 1);
    }

    if (hsb) hsb[(size_t)b * 1024 + dcol + m0 + j] = f2bf(hn);
    if (csd) csd[(size_t)b * HSTR + dcol + m0 + j] = c;
}

// ---------------- log-softmax: merge partials + normalize, one kernel ----------------
__global__ __launch_bounds__(256) void lsm_norm_kernel(
    float* __restrict__ x, const float* __restrict__ part, int nt, int n4)
{
    __shared__ float ms[256], ss[256];
    const int tid = threadIdx.x;
    float m = -3.0e38f, s = 0.f;
    for (int t = tid; t < nt; t += 256) {
        const float mo = part[((size_t)blockIdx.x * nt + t) * 2];
        const float so = part[((size_t)blockIdx.x * nt + t) * 2 + 1];
        const float M = fmaxf(m, mo);
        s = s * expf(m - M) + so * expf(mo - M);
        m = M;
    }
    ms[tid] = m; ss[tid] = s;
    __syncthreads();
    for (int off = 128; off > 0; off >>= 1) {
        if (tid < off) {
            const float m2 = ms[tid + off], s2 = ss[tid + off];
            const float m1 = ms[tid],       s1 = ss[tid];
            const float M = fmaxf(m1, m2);
            ss[tid] = s1 * expf(m1 - M) + s2 * expf(m2 - M);
            ms[tid] = M;
        }
        __syncthreads();
    }
    const float ML = ms[0] + logf(ss[0]);
    float4* p = reinterpret_cast<float4*>(x + (size_t)blockIdx.x * (n4 * 4));
    for (int cc = tid; cc < n4; cc += 256) {
        float4 v = p[cc];
        v.x -= ML; v.y -= ML; v.z -= ML; v.w -= ML;
        p[cc] = v;
    }
}

// ---------------- host-side orchestration ----------------
extern "C" void kernel_launch(void* const* d_in, const int* in_sizes, int n_in,
                              void* d_out, int out_size, void* d_ws, size_t ws_size,
                              hipStream_t stream)
{
    const int*   sent  = (const int*)d_in[0];
    const int*   targ  = (const int*)d_in[1];
    const float* emb   = (const float*)d_in[2];
    const float* e0Wih = (const float*)d_in[3];
    const float* e0Whh = (const float*)d_in[4];
    const float* e0bih = (const float*)d_in[5];
    const float* e0bhh = (const float*)d_in[6];
    const float* e1Wih = (const float*)d_in[7];
    const float* e1Whh = (const float*)d_in[8];
    const float* e1bih = (const float*)d_in[9];
    const float* e1bhh = (const float*)d_in[10];
    const float* d0Wih = (const float*)d_in[11];
    const float* d0Whh = (const float*)d_in[12];
    const float* d0bih = (const float*)d_in[13];
    const float* d0bhh = (const float*)d_in[14];
    const float* d1Wih = (const float*)d_in[15];
    const float* d1Whh = (const float*)d_in[16];
    const float* d1bih = (const float*)d_in[17];
    const float* d1bhh = (const float*)d_in[18];
    const float* Wout  = (const float*)d_in[19];
    const float* bout  = (const float*)d_in[20];

    float* ws  = (float*)d_ws;
    float* xwA = ws + WS_XWA;
    float* xwB = ws + WS_XWB;
    float* cs  = ws + WS_CS;
    int*   bar = (int*)(ws + WS_BAR);
    unsigned short* ub    = (unsigned short*)(ws + WS_BF);
    unsigned short* x0b   = ub + U_X0B;
    unsigned short* h_e0  = ub + U_HE0;
    unsigned short* h_e1  = ub + U_HE1;
    unsigned short* h_d0  = ub + U_HD0;
    unsigned short* h_d1  = ub + U_HD1;
    unsigned short* hsb   = ub + U_HSB;
    unsigned short* e0Wb  = ub + U_E0W;
    unsigned short* e1Wb  = ub + U_E1W;
    unsigned short* d0Wb  = ub + U_D0W;
    unsigned short* d1Wb  = ub + U_D1W;
    unsigned short* Woutb = (unsigned short*)xwA;
    float* out = (float*)d_out;

    hipMemsetAsync(bar, 0, 4 * 8192 * sizeof(int), stream);

    // ---- weight conversions (fp32 -> bf16), one kernel ----
    f2b_multi_kernel<<<1280, 256, 0, stream>>>(e0Wih, e0Wb, e1Wih, e1Wb,
                                               d0Wih, d0Wb, d1Wih, d1Wb);

    // ---- encoder layer 0 (both dirs in ONE GEMM: N=4096, dir1 cols at 2048) ----
    embed_src_kernel<<<(S_LEN * BSZ) / 4, 256, 0, stream>>>(sent, emb, x0b);
    gemm_bf16_kernel<<<64 * 32, 256, 0, stream>>>(x0b, e0Wb, e0bih, e0bhh, xwA,
                                                  S_LEN * BSZ, 4096, EMBD, 32);
    lstm_mfma_scan<512><<<256, 256, 0, stream>>>(xwA, xwA + 2048 * 64,
                                                 e0Whh, e0Whh + 2048ull * 512,
                                                 nullptr, nullptr, h_e0,
                                                 hsb, cs, S_LEN, 2, 2, bar);
    // ---- encoder layer 1 (final states only) ----
    gemm_bf16_kernel<<<64 * 32, 256, 0, stream>>>(h_e0, e1Wb, e1bih, e1bhh, xwA,
                                                  S_LEN * BSZ, 4096, 2 * HID_, 32);
    lstm_mfma_scan<512><<<256, 256, 0, stream>>>(xwA, xwA + 2048 * 64,
                                                 e1Whh, e1Whh + 2048ull * 512,
                                                 nullptr, nullptr, h_e1,
                                                 hsb + 65536, cs + 65536,
                                                 S_LEN, 2, 2, bar + 8192);
    // ---- decoder layer 0 ----
    embed_dec_kernel<<<(T_LEN * BSZ) / 4, 256, 0, stream>>>(sent, targ, emb, x0b);
    gemm_bf16_kernel<<<32 * 32, 256, 0, stream>>>(x0b, d0Wb, d0bih, d0bhh, xwA,
                                                  T_LEN * BSZ, 4 * DHID_, EMBD, 32);
    lstm_mfma_scan<1024><<<256, 256, 0, stream>>>(xwA, nullptr, d0Whh, nullptr,
                                                  hsb, cs, h_d0,
                                                  nullptr, nullptr, T_LEN, 1, 0,
                                                  bar + 2 * 8192);
    // ---- Wout -> bf16 (xwA region free after dec0 scan) ----
    f2b_kernel<<<2048, 256, 0, stream>>>(Wout, Woutb, (VOC_ * DHID_) / 4);
    // ---- decoder layer 1 ----
    gemm_bf16_kernel<<<32 * 32, 256, 0, stream>>>(h_d0, d1Wb, d1bih, d1bhh, xwB,
                                                  T_LEN * BSZ, 4 * DHID_, DHID_, 32);
    lstm_mfma_scan<1024><<<256, 256, 0, stream>>>(xwB, nullptr, d1Whh, nullptr,
                                                  hsb + 65536, cs + 65536, h_d1,
                                                  nullptr, nullptr, T_LEN, 1, 0,
                                                  bar + 3 * 8192);
    // ---- vocab projection (128x256 tile, fused softmax partials) + merge+normalize ----
    gemm_logits_kernel<<<32 * 125, 256, 0, stream>>>(h_d1, Woutb, bout, out,
                                                     T_LEN * BSZ, VOC_, DHID_, xwB);
    lsm_norm_kernel<<<T_LEN * BSZ, 256, 0, stream>>>(out, xwB, 250, VOC_ / 4);
}

// Round 17
// 2528.473 us; speedup vs baseline: 1.0490x; 1.0482x over previous
//
#include <hip/hip_runtime.h>

#define S_LEN 128
#define T_LEN 64
#define BSZ   64
#define EMBD  256
#define HID_  512
#define DHID_ 1024
#define VOC_  32000
#define HSTR  1024

typedef float  f4_t  __attribute__((ext_vector_type(4)));
typedef float  f32x4 __attribute__((ext_vector_type(4)));
typedef short  s16x8 __attribute__((ext_vector_type(8)));
typedef __bf16 bf16x8 __attribute__((ext_vector_type(8)));
typedef unsigned short u16x4 __attribute__((ext_vector_type(4)));
typedef int    i32x2 __attribute__((ext_vector_type(2)));

// ---------------- workspace layout ----------------
// float offsets:
#define WS_XWA  0ull
#define WS_XWB  (WS_XWA + 16777216ull)
#define WS_CS   (WS_XWB + 16777216ull)
#define WS_BAR  (WS_CS  + 131072ull)
#define WS_BF   (WS_BAR + 32768ull)
// ushort offsets within bf16 region:
#define U_X0B   0ull
#define U_HE0   (U_X0B + 2097152ull)
#define U_HE1   (U_HE0 + 8388608ull)
#define U_HD0   (U_HE1 + 8388608ull)
#define U_HD1   (U_HD0 + 4194304ull)
#define U_HSB   (U_HD1 + 4194304ull)
#define U_E0W   (U_HSB + 131072ull)
#define U_E1W   (U_E0W + 1048576ull)
#define U_D0W   (U_E1W + 4194304ull)
#define U_D1W   (U_D0W + 1048576ull)

__device__ __forceinline__ unsigned short f2bf(float x) {
    unsigned u = __builtin_bit_cast(unsigned, x);
    return (unsigned short)((u + 0x7fffu + ((u >> 16) & 1u)) >> 16);
}

// ---------------- coherent (LLC-scope) memory helpers ----------------
__device__ __forceinline__ f4_t sc_load4(const void* p) {
    f4_t v;
    asm volatile("global_load_dwordx4 %0, %1, off sc0 sc1" : "=v"(v) : "v"(p));
    return v;                               // NOT ready until a vmcnt wait
}
__device__ __forceinline__ int sc_load1(const int* p) {
    int v;
    asm volatile("global_load_dword %0, %1, off sc0 sc1\n\ts_waitcnt vmcnt(0)"
                 : "=v"(v) : "v"(p) : "memory");
    return v;
}
__device__ __forceinline__ void sc_store_int(int* p, int v) {
    asm volatile("global_store_dword %0, %1, off sc0 sc1" :: "v"(p), "v"(v) : "memory");
}
__device__ __forceinline__ void sc_store8(void* p, i32x2 v) {
    asm volatile("global_store_dwordx2 %0, %1, off sc0 sc1" :: "v"(p), "v"(v) : "memory");
}
__device__ __forceinline__ void nt_store1(float* p, float v) {   // non-temporal: no write-allocate
    asm volatile("global_store_dword %0, %1, off nt" :: "v"(p), "v"(v) : "memory");
}
__device__ __forceinline__ void nt_store4(float* p, f4_t v) {
    asm volatile("global_store_dwordx4 %0, %1, off nt" :: "v"(p), "v"(v) : "memory");
}
__device__ __forceinline__ float g_load1(const float* p) {   // plain cached load, no wait
    float v;
    asm volatile("global_load_dword %0, %1, off" : "=v"(v) : "v"(p));
    return v;
}
__device__ __forceinline__ void wait_vm0() {
    asm volatile("s_waitcnt vmcnt(0)" ::: "memory");
}
__device__ __forceinline__ void wait_vm8() {
    asm volatile("s_waitcnt vmcnt(8)" ::: "memory");
}

__device__ __forceinline__ void gload_lds16(const void* g, void* l) {
    __builtin_amdgcn_global_load_lds(
        (const __attribute__((address_space(1))) void*)g,
        (__attribute__((address_space(3))) void*)l, 16, 0, 0);
}

__device__ __forceinline__ float sigmoidf_(float x) { return 1.f / (1.f + expf(-x)); }

// ---------------- fp32 -> bf16 conversion (single kernel, 4 weight segments) ----------------
__global__ __launch_bounds__(256) void f2b_multi_kernel(
    const float* __restrict__ p0, unsigned short* __restrict__ q0,
    const float* __restrict__ p1, unsigned short* __restrict__ q1,
    const float* __restrict__ p2, unsigned short* __restrict__ q2,
    const float* __restrict__ p3, unsigned short* __restrict__ q3)
{
    const int stride = gridDim.x * 256;
    for (int i = blockIdx.x * 256 + threadIdx.x; i < 2621440; i += stride) {
        const float* in; unsigned short* out; int o;
        if (i < 262144)       { in = p0; out = q0; o = i; }
        else if (i < 1310720) { in = p1; out = q1; o = i - 262144; }
        else if (i < 1572864) { in = p2; out = q2; o = i - 1310720; }
        else                  { in = p3; out = q3; o = i - 1572864; }
        const float4 v = reinterpret_cast<const float4*>(in)[o];
        u16x4 w = { f2bf(v.x), f2bf(v.y), f2bf(v.z), f2bf(v.w) };
        reinterpret_cast<u16x4*>(out)[o] = w;
    }
}

__global__ __launch_bounds__(256) void f2b_kernel(
    const float* __restrict__ in, unsigned short* __restrict__ out, int n4)
{
    const int stride = gridDim.x * 256;
    for (int i = blockIdx.x * 256 + threadIdx.x; i < n4; i += stride) {
        const float4 v = reinterpret_cast<const float4*>(in)[i];
        u16x4 o = { f2bf(v.x), f2bf(v.y), f2bf(v.z), f2bf(v.w) };
        reinterpret_cast<u16x4*>(out)[i] = o;
    }
}

// ---------------- embedding gathers (emit bf16), 4 tokens per 256-thr block ----------------
__global__ __launch_bounds__(256) void embed_src_kernel(
    const int* __restrict__ toks, const float* __restrict__ emb,
    unsigned short* __restrict__ out)
{
    const int i = blockIdx.x * 4 + (threadIdx.x >> 6);
    const int lane = threadIdx.x & 63;
    const int tok = toks[i];
    const float4 v = reinterpret_cast<const float4*>(emb + (size_t)tok * EMBD)[lane];
    u16x4 o = { f2bf(v.x), f2bf(v.y), f2bf(v.z), f2bf(v.w) };
    reinterpret_cast<u16x4*>(out + (size_t)i * EMBD)[lane] = o;
}

__global__ __launch_bounds__(256) void embed_dec_kernel(
    const int* __restrict__ sent, const int* __restrict__ targ,
    const float* __restrict__ emb, unsigned short* __restrict__ out)
{
    const int i = blockIdx.x * 4 + (threadIdx.x >> 6);
    const int lane = threadIdx.x & 63;
    const int t = i >> 6, b = i & 63;
    const int tok = (t == 0) ? sent[(S_LEN - 1) * BSZ + b] : targ[(t - 1) * BSZ + b];
    const float4 v = reinterpret_cast<const float4*>(emb + (size_t)tok * EMBD)[lane];
    u16x4 o = { f2bf(v.x), f2bf(v.y), f2bf(v.z), f2bf(v.w) };
    reinterpret_cast<u16x4*>(out + (size_t)i * EMBD)[lane] = o;
}

// ---------------- bf16 MFMA GEMM:  C = A[M,K] * B[N,K]^T + b1 (+ b2) ----------------
// tmode 0: C fp32 row-major (M,N), nt stores (no write-allocate); optional softmax partials.
// tmode 1: C fp32 as (M/64, N, 64) = (T,N,B).
__global__ __launch_bounds__(256) void gemm_bf16_kernel(
    const unsigned short* __restrict__ A, const unsigned short* __restrict__ B,
    const float* __restrict__ b1, const float* __restrict__ b2,
    float* __restrict__ C, int M, int N, int K, int nTN, int tmode,
    float* __restrict__ part)
{
    __shared__ __align__(16) unsigned short As[128 * 64];
    __shared__ __align__(16) unsigned short Bs[128 * 64];
    __shared__ float prt[2][128][2];

    const int tid  = threadIdx.x;
    const int lane = tid & 63;
    const int wv   = tid >> 6;
    const int wm   = wv >> 1, wn = wv & 1;

    const int nwg = gridDim.x;
    const int q = nwg >> 3, r = nwg & 7;
    const int xcd = blockIdx.x & 7, io = blockIdx.x >> 3;
    const int wg = (xcd < r ? xcd * (q + 1) : r * (q + 1) + (xcd - r) * q) + io;
    const int bm = (wg / nTN) * 128;
    const int bn = (wg % nTN) * 128;

    f32x4 acc[4][4];
#pragma unroll
    for (int i = 0; i < 4; ++i)
#pragma unroll
        for (int j = 0; j < 4; ++j) acc[i][j] = (f32x4)0.f;

    const int lin_base = wv * 1024 + lane * 16;

    for (int k0 = 0; k0 < K; k0 += 64) {
        __syncthreads();
#pragma unroll
        for (int qc = 0; qc < 4; ++qc) {
            const int lin = qc * 4096 + lin_base;
            const int row = lin >> 7;
            const int c   = (lin >> 4) & 7;
            const int sc  = c ^ (row & 7);
            const size_t gofs  = (size_t)(bm + row) * K + k0 + sc * 8;
            const size_t gofsB = (size_t)(bn + row) * K + k0 + sc * 8;
            char* ldst  = (char*)As + qc * 4096 + wv * 1024;
            char* ldstB = (char*)Bs + qc * 4096 + wv * 1024;
            gload_lds16(A + gofs, ldst);
            gload_lds16(B + gofsB, ldstB);
        }
        asm volatile("s_waitcnt vmcnt(0)" ::: "memory");
        __syncthreads();
#pragma unroll
        for (int ks = 0; ks < 2; ++ks) {
            bf16x8 af[4], bfv[4];
            const int ca = ks * 4 + (lane >> 4);
#pragma unroll
            for (int f = 0; f < 4; ++f) {
                const int ra = wm * 64 + f * 16 + (lane & 15);
                af[f] = __builtin_bit_cast(bf16x8,
                    *(const s16x8*)((const char*)As + ra * 128 + ((ca ^ (ra & 7)) << 4)));
                const int rb = wn * 64 + f * 16 + (lane & 15);
                bfv[f] = __builtin_bit_cast(bf16x8,
                    *(const s16x8*)((const char*)Bs + rb * 128 + ((ca ^ (rb & 7)) << 4)));
            }
#pragma unroll
            for (int i = 0; i < 4; ++i)
#pragma unroll
                for (int j = 0; j < 4; ++j)
                    acc[i][j] = __builtin_amdgcn_mfma_f32_16x16x32_bf16(
                        af[i], bfv[j], acc[i][j], 0, 0, 0);
        }
    }

    const int col0 = bn + wn * 64 + (lane & 15);
    if (tmode == 0) {
        const int row0 = bm + wm * 64 + ((lane >> 4) << 2);
        float bs[4];
#pragma unroll
        for (int j = 0; j < 4; ++j) {
            const int col = col0 + j * 16;
            bs[j] = b1[col];
            if (b2) bs[j] += b2[col];
        }
#pragma unroll
        for (int i = 0; i < 4; ++i)
#pragma unroll
            for (int j = 0; j < 4; ++j)
#pragma unroll
                for (int rg = 0; rg < 4; ++rg)
                    nt_store1(&C[(size_t)(row0 + i * 16 + rg) * N + col0 + j * 16],
                              acc[i][j][rg] + bs[j]);

        if (part) {
            float pm[4][4], ps[4][4];
#pragma unroll
            for (int i = 0; i < 4; ++i)
#pragma unroll
                for (int rg = 0; rg < 4; ++rg) {
                    float m = acc[i][0][rg] + bs[0];
                    m = fmaxf(m, acc[i][1][rg] + bs[1]);
                    m = fmaxf(m, acc[i][2][rg] + bs[2]);
                    m = fmaxf(m, acc[i][3][rg] + bs[3]);
                    pm[i][rg] = m;
                }
#pragma unroll
            for (int mask = 1; mask <= 8; mask <<= 1)
#pragma unroll
                for (int i = 0; i < 4; ++i)
#pragma unroll
                    for (int rg = 0; rg < 4; ++rg)
                        pm[i][rg] = fmaxf(pm[i][rg], __shfl_xor(pm[i][rg], mask));
#pragma unroll
            for (int i = 0; i < 4; ++i)
#pragma unroll
                for (int rg = 0; rg < 4; ++rg) {
                    float s = 0.f;
#pragma unroll
                    for (int j = 0; j < 4; ++j)
                        s += expf(acc[i][j][rg] + bs[j] - pm[i][rg]);
                    ps[i][rg] = s;
                }
#pragma unroll
            for (int mask = 1; mask <= 8; mask <<= 1)
#pragma unroll
                for (int i = 0; i < 4; ++i)
#pragma unroll
                    for (int rg = 0; rg < 4; ++rg)
                        ps[i][rg] += __shfl_xor(ps[i][rg], mask);
            if ((lane & 15) == 0) {
#pragma unroll
                for (int i = 0; i < 4; ++i)
#pragma unroll
                    for (int rg = 0; rg < 4; ++rg) {
                        const int r64 = ((lane >> 4) << 2) + i * 16 + rg;
                        prt[wn][wm * 64 + r64][0] = pm[i][rg];
                        prt[wn][wm * 64 + r64][1] = ps[i][rg];
                    }
            }
            __syncthreads();
            if (tid < 128) {
                const float m0_ = prt[0][tid][0], s0_ = prt[0][tid][1];
                const float m1_ = prt[1][tid][0], s1_ = prt[1][tid][1];
                const float Mx = fmaxf(m0_, m1_);
                const float Sx = s0_ * expf(m0_ - Mx) + s1_ * expf(m1_ - Mx);
                const size_t o = ((size_t)(bm + tid) * nTN + (bn >> 7)) * 2;
                part[o] = Mx; part[o + 1] = Sx;
            }
        }
    } else {
        const int tblk = (bm >> 6) + wm;
        const int rb = (lane >> 4) << 2;
#pragma unroll
        for (int i = 0; i < 4; ++i) {
#pragma unroll
            for (int j = 0; j < 4; ++j) {
                const int col = col0 + j * 16;
                float bias = b1[col];
                if (b2) bias += b2[col];
                float4 v = { acc[i][j][0] + bias, acc[i][j][1] + bias,
                             acc[i][j][2] + bias, acc[i][j][3] + bias };
                *reinterpret_cast<float4*>(&C[((size_t)tblk * N + col) * 64 + rb + i * 16]) = v;
            }
        }
    }
}

// ---------------- persistent MFMA LSTM scan, WAVE-SCOPED producer polling (R14) ----------------
template<int H_T>
__global__ __launch_bounds__(256, 1) void lstm_mfma_scan(
    const float* __restrict__ xw0, const float* __restrict__ xw1,
    const float* __restrict__ Whh0, const float* __restrict__ Whh1,
    const unsigned short* __restrict__ h0b, const float* __restrict__ c0,
    unsigned short* __restrict__ hist,
    unsigned short* __restrict__ hsb, float* __restrict__ csd,
    int T, int ndir, int rev_mask, int* bar)
{
    constexpr int KST = H_T / 32;
    constexpr int CH  = H_T / 8;
    constexpr int CPW = CH / 4;
    constexpr int NB  = CPW / 8;

    __shared__ __align__(16) unsigned short h_lds[64 * H_T];
    __shared__ float pre[64][17];
    __shared__ __align__(8) unsigned short hpack[64][4];

    const int tid  = threadIdx.x;
    const int lane = tid & 63;
    const int w    = tid >> 6;
    const int bpd  = (ndir == 2) ? 128 : 256;
    const int dir  = blockIdx.x / bpd;
    const int blk  = blockIdx.x - dir * bpd;
    const int m0   = blk * 4;
    const int rev  = (rev_mask >> dir) & 1;
    const float* xw  = dir ? xw1  : xw0;
    const float* Whh = dir ? Whh1 : Whh0;
    const int dcol = dir * H_T;
    const int b = tid & 63;
    const int j = tid >> 6;

    int* myflag = bar + blockIdx.x * 32;
    const int* pflag = bar + (dir * bpd + w * 2 * CPW + (lane % (2 * CPW))) * 32;
    const int scc = w * CPW + (lane % CPW);
    const int sr0 = (lane / CPW) * CPW;

    const int n  = lane & 15;
    const int kg = lane >> 4;
    const int wr = (n >> 2) * H_T + m0 + (n & 3);
    s16x8 wfr[KST];
#pragma unroll
    for (int ks = 0; ks < KST; ++ks) {
        const float* wp = Whh + (size_t)wr * H_T + ks * 32 + kg * 8;
        const float4 lo = *reinterpret_cast<const float4*>(wp);
        const float4 hi = *reinterpret_cast<const float4*>(wp + 4);
        s16x8 rr;
        rr[0] = (short)f2bf(lo.x); rr[1] = (short)f2bf(lo.y);
        rr[2] = (short)f2bf(lo.z); rr[3] = (short)f2bf(lo.w);
        rr[4] = (short)f2bf(hi.x); rr[5] = (short)f2bf(hi.y);
        rr[6] = (short)f2bf(hi.z); rr[7] = (short)f2bf(hi.w);
        wfr[ks] = rr;
    }

    float c  = c0 ? c0[(size_t)b * HSTR + dcol + m0 + j] : 0.f;
    float hn = 0.f;
    const int rA  = w * 16 + n;
    const int rAx = rA & 7;

    for (int s = 0; s < T; ++s) {
        const int tt = rev ? (T - 1 - s) : s;

        const float* xb = xw + ((size_t)tt * 4096 + m0 + j) * 64 + b;
        float xg0 = g_load1(xb);
        float xg1 = g_load1(xb + (size_t)H_T * 64);
        float xg2 = g_load1(xb + (size_t)2 * H_T * 64);
        float xg3 = g_load1(xb + (size_t)3 * H_T * 64);

        if (s > 0) {
            for (;;) {
                const int f = sc_load1(pflag);
                if (__all(f >= s)) break;
            }
        }

        const unsigned short* hb;
        size_t tofs;
        if (s == 0) { hb = h0b; tofs = 0; }
        else {
            const int tp = rev ? (tt + 1) : (tt - 1);
            hb = hist; tofs = (size_t)tp * (64 * 1024);
        }

        float p0 = 0.f, p1 = 0.f, p2 = 0.f, p3 = 0.f;
        if (hb) {
            const unsigned short* src = hb + tofs + dcol + scc * 8;
            f4_t bufA[8], bufB[8];
            auto issue = [&](f4_t (&bf)[8], int bt) {
#pragma unroll
                for (int jj = 0; jj < 8; ++jj) {
                    const int rr_ = sr0 + bt * 8 + jj;
                    bf[jj] = sc_load4(src + (size_t)rr_ * 1024);
                }
            };
            auto writeb = [&](const f4_t (&bf)[8], int bt) {
#pragma unroll
                for (int jj = 0; jj < 8; ++jj) {
                    const int rr_ = sr0 + bt * 8 + jj;
                    const int off = rr_ * (2 * H_T) + ((scc ^ (rr_ & 7)) << 4);
                    *(f4_t*)((char*)h_lds + off) = bf[jj];
                }
            };
            issue(bufA, 0);
            if (NB > 1) issue(bufB, 1);
#pragma unroll
            for (int bt = 0; bt < NB; ++bt) {
                if (bt + 1 < NB) wait_vm8(); else wait_vm0();
                if (bt & 1) writeb(bufB, bt); else writeb(bufA, bt);
                if (bt + 2 < NB) { if (bt & 1) issue(bufB, bt + 2); else issue(bufA, bt + 2); }
            }
            __syncthreads();

            f32x4 acc = {0.f, 0.f, 0.f, 0.f};
#pragma unroll
            for (int ks = 0; ks < KST; ++ks) {
                const int cc_ = ks * 4 + kg;
                const int off = rA * (2 * H_T) + ((cc_ ^ rAx) << 4);
                const bf16x8 a = __builtin_bit_cast(bf16x8,
                    *(const s16x8*)((const char*)h_lds + off));
                acc = __builtin_amdgcn_mfma_f32_16x16x32_bf16(
                    a, __builtin_bit_cast(bf16x8, wfr[ks]), acc, 0, 0, 0);
            }
#pragma unroll
            for (int rg = 0; rg < 4; ++rg)
                pre[w * 16 + kg * 4 + rg][n] = acc[rg];
            __syncthreads();
            p0 = pre[b][0 + j]; p1 = pre[b][4 + j];
            p2 = pre[b][8 + j]; p3 = pre[b][12 + j];
        }

        asm volatile("s_waitcnt vmcnt(0)"
                     : "+v"(xg0), "+v"(xg1), "+v"(xg2), "+v"(xg3) :: "memory");

        const float ig = sigmoidf_(p0 + xg0);
        const float fg = sigmoidf_(p1 + xg1);
        const float gg = tanhf(p2 + xg2);
        const float og = sigmoidf_(p3 + xg3);
        c  = fg * c + ig * gg;
        hn = og * tanhf(c);

        hpack[b][j] = f2bf(hn);
        __syncthreads();
        if (tid < 64) {
            const i32x2 v2 = *reinterpret_cast<const i32x2*>(&hpack[tid][0]);
            sc_store8(hist + (size_t)tt * (64 * 1024) + (size_t)tid * 1024 + dcol + m0, v2);
        }
        wait_vm0();
        if (s + 1 < T && tid == 0) sc_store_int(myflag, s + 1);
    }

    if (hsb) hsb[(size_t)b * 1024 + dcol + m0 + j] = f2bf(hn);
    if (csd) csd[(size_t)b * HSTR + dcol + m0 + j] = c;
}

// ---------------- log-softmax: merge partials + normalize, one kernel ----------------
__global__ __launch_bounds__(256) void lsm_norm_kernel(
    float* __restrict__ x, const float* __restrict__ part, int nt, int n4)
{
    __shared__ float ms[256], ss[256];
    const int tid = threadIdx.x;
    float m = -3.0e38f, s = 0.f;
    for (int t = tid; t < nt; t += 256) {
        const float mo = part[((size_t)blockIdx.x * nt + t) * 2];
        const float so = part[((size_t)blockIdx.x * nt + t) * 2 + 1];
        const float M = fmaxf(m, mo);
        s = s * expf(m - M) + so * expf(mo - M);
        m = M;
    }
    ms[tid] = m; ss[tid] = s;
    __syncthreads();
    for (int off = 128; off > 0; off >>= 1) {
        if (tid < off) {
            const float m2 = ms[tid + off], s2 = ss[tid + off];
            const float m1 = ms[tid],       s1 = ss[tid];
            const float M = fmaxf(m1, m2);
            ss[tid] = s1 * expf(m1 - M) + s2 * expf(m2 - M);
            ms[tid] = M;
        }
        __syncthreads();
    }
    const float ML = ms[0] + logf(ss[0]);
    float4* p = reinterpret_cast<float4*>(x + (size_t)blockIdx.x * (n4 * 4));
    for (int cc = tid; cc < n4; cc += 256) {
        float4 v = p[cc];
        f4_t o = { v.x - ML, v.y - ML, v.z - ML, v.w - ML };
        nt_store4(reinterpret_cast<float*>(p + cc), o);
    }
}

// ---------------- host-side orchestration ----------------
extern "C" void kernel_launch(void* const* d_in, const int* in_sizes, int n_in,
                              void* d_out, int out_size, void* d_ws, size_t ws_size,
                              hipStream_t stream)
{
    const int*   sent  = (const int*)d_in[0];
    const int*   targ  = (const int*)d_in[1];
    const float* emb   = (const float*)d_in[2];
    const float* e0Wih = (const float*)d_in[3];
    const float* e0Whh = (const float*)d_in[4];
    const float* e0bih = (const float*)d_in[5];
    const float* e0bhh = (const float*)d_in[6];
    const float* e1Wih = (const float*)d_in[7];
    const float* e1Whh = (const float*)d_in[8];
    const float* e1bih = (const float*)d_in[9];
    const float* e1bhh = (const float*)d_in[10];
    const float* d0Wih = (const float*)d_in[11];
    const float* d0Whh = (const float*)d_in[12];
    const float* d0bih = (const float*)d_in[13];
    const float* d0bhh = (const float*)d_in[14];
    const float* d1Wih = (const float*)d_in[15];
    const float* d1Whh = (const float*)d_in[16];
    const float* d1bih = (const float*)d_in[17];
    const float* d1bhh = (const float*)d_in[18];
    const float* Wout  = (const float*)d_in[19];
    const float* bout  = (const float*)d_in[20];

    float* ws  = (float*)d_ws;
    float* xwA = ws + WS_XWA;
    float* xwB = ws + WS_XWB;
    float* cs  = ws + WS_CS;
    int*   bar = (int*)(ws + WS_BAR);
    unsigned short* ub    = (unsigned short*)(ws + WS_BF);
    unsigned short* x0b   = ub + U_X0B;
    unsigned short* h_e0  = ub + U_HE0;
    unsigned short* h_e1  = ub + U_HE1;
    unsigned short* h_d0  = ub + U_HD0;
    unsigned short* h_d1  = ub + U_HD1;
    unsigned short* hsb   = ub + U_HSB;
    unsigned short* e0Wb  = ub + U_E0W;
    unsigned short* e1Wb  = ub + U_E1W;
    unsigned short* d0Wb  = ub + U_D0W;
    unsigned short* d1Wb  = ub + U_D1W;
    unsigned short* Woutb = (unsigned short*)xwA;
    float* out = (float*)d_out;

    hipMemsetAsync(bar, 0, 4 * 8192 * sizeof(int), stream);

    // ---- weight conversions (fp32 -> bf16), one kernel ----
    f2b_multi_kernel<<<1280, 256, 0, stream>>>(e0Wih, e0Wb, e1Wih, e1Wb,
                                               d0Wih, d0Wb, d1Wih, d1Wb);

    // ---- encoder layer 0 (both dirs in ONE GEMM: N=4096, dir1 cols at 2048) ----
    embed_src_kernel<<<(S_LEN * BSZ) / 4, 256, 0, stream>>>(sent, emb, x0b);
    gemm_bf16_kernel<<<64 * 32, 256, 0, stream>>>(x0b, e0Wb, e0bih, e0bhh, xwA,
                                                  S_LEN * BSZ, 4096, EMBD, 32, 1, nullptr);
    lstm_mfma_scan<512><<<256, 256, 0, stream>>>(xwA, xwA + 2048 * 64,
                                                 e0Whh, e0Whh + 2048ull * 512,
                                                 nullptr, nullptr, h_e0,
                                                 hsb, cs, S_LEN, 2, 2, bar);
    // ---- encoder layer 1 (final states only) ----
    gemm_bf16_kernel<<<64 * 32, 256, 0, stream>>>(h_e0, e1Wb, e1bih, e1bhh, xwA,
                                                  S_LEN * BSZ, 4096, 2 * HID_, 32, 1, nullptr);
    lstm_mfma_scan<512><<<256, 256, 0, stream>>>(xwA, xwA + 2048 * 64,
                                                 e1Whh, e1Whh + 2048ull * 512,
                                                 nullptr, nullptr, h_e1,
                                                 hsb + 65536, cs + 65536,
                                                 S_LEN, 2, 2, bar + 8192);
    // ---- decoder layer 0 ----
    embed_dec_kernel<<<(T_LEN * BSZ) / 4, 256, 0, stream>>>(sent, targ, emb, x0b);
    gemm_bf16_kernel<<<32 * 32, 256, 0, stream>>>(x0b, d0Wb, d0bih, d0bhh, xwA,
                                                  T_LEN * BSZ, 4 * DHID_, EMBD, 32, 1, nullptr);
    lstm_mfma_scan<1024><<<256, 256, 0, stream>>>(xwA, nullptr, d0Whh, nullptr,
                                                  hsb, cs, h_d0,
                                                  nullptr, nullptr, T_LEN, 1, 0,
                                                  bar + 2 * 8192);
    // ---- Wout -> bf16 (xwA region free after dec0 scan) ----
    f2b_kernel<<<2048, 256, 0, stream>>>(Wout, Woutb, (VOC_ * DHID_) / 4);
    // ---- decoder layer 1 ----
    gemm_bf16_kernel<<<32 * 32, 256, 0, stream>>>(h_d0, d1Wb, d1bih, d1bhh, xwB,
                                                  T_LEN * BSZ, 4 * DHID_, DHID_, 32, 1, nullptr);
    lstm_mfma_scan<1024><<<256, 256, 0, stream>>>(xwB, nullptr, d1Whh, nullptr,
                                                  hsb + 65536, cs + 65536, h_d1,
                                                  nullptr, nullptr, T_LEN, 1, 0,
                                                  bar + 3 * 8192);
    // ---- vocab projection (fused softmax partials) + merge+normalize ----
    gemm_bf16_kernel<<<32 * 250, 256, 0, stream>>>(h_d1, Woutb, bout, nullptr, out,
                                                   T_LEN * BSZ, VOC_, DHID_, 250, 0, xwB);
    lsm_norm_kernel<<<T_LEN * BSZ, 256, 0, stream>>>(out, xwB, 250, VOC_ / 4);
}